// Round 11
// baseline (153.067 us; speedup 1.0000x reference)
//
#include <hip/hip_runtime.h>
#include <math.h>

#define C 8192
#define D 1024
#define BATCH 1024
#define PM 0.95f
#define PMC 0.05f
// int8 quant with scale 127 per side; dot comes out 16129x too big.
// epilogue uses 10/16129 (INVT = 1/TEMP = 10).
#define INVT_I8 (10.0f / 16129.0f)

typedef unsigned char u8;
typedef __attribute__((ext_vector_type(16))) int i32x16;
typedef __attribute__((ext_vector_type(4))) int i32x4;

#define GLOBAL_AS(p) ((const __attribute__((address_space(1))) void*)(p))
#define LDS_AS(p) ((__attribute__((address_space(3))) void*)(p))

// ---------------------------------------------------------------------------
// EMA + int8 quantize (r23 exact, verified). 512 blocks x 16 consecutive
// classes; LDS-staged quantize + block-cooperative coalesced writeback.
// int8 layout (1-KB k-chunks per 32-row group, 16-B lane units for
// mfma_i32_32x32x32_i8, k = (l>>5)*16 + [0,16) contiguous):
//   element (row c, k) ->
//     P8[(c>>5)*32768 + (k>>5)*1024 + ((k>>4)&1)*512 + (c&31)*16 + (k&15)]
__global__ __launch_bounds__(256) void ema_split_kernel(const float* __restrict__ feat,
                                                        const int* __restrict__ labels,
                                                        const float* __restrict__ protos,
                                                        u8* __restrict__ P8,
                                                        float* __restrict__ rowsum,
                                                        float* __restrict__ out) {
    __shared__ int sl[BATCH];
    __shared__ unsigned int sq[64][16][4];    // [16B-piece][class-in-block][word]  16 KB
    const int t = threadIdx.x, w = t >> 6, lane = t & 63;
    const int cb = blockIdx.x * 16;

    if (blockIdx.x < 32) rowsum[blockIdx.x * 256 + t] = 0.0f;
    if (blockIdx.x == 0 && t == 0) out[0] = 0.0f;

    for (int i = t; i < BATCH; i += 256) sl[i] = labels[i];
    __syncthreads();

    for (int i = 0; i < 4; ++i) {
        const int c = cb + w * 4 + i;

        float4 v[4];
        #pragma unroll
        for (int s = 0; s < 4; ++s)
            v[s] = *(const float4*)(protos + (size_t)c * D + s * 256 + lane * 4);

        for (int base = 0; base < BATCH; base += 64) {
            unsigned long long mask = __ballot(sl[base + lane] == c);
            while (mask) {
                const int b = __ffsll((long long)mask) - 1;
                mask &= mask - 1;
                const int idx = base + b;
                float ss = 0.0f;
                #pragma unroll
                for (int s = 0; s < 4; ++s) {
                    const float4 f = *(const float4*)(feat + (size_t)idx * D + s * 256 + lane * 4);
                    v[s].x = v[s].x * PM + f.x * PMC;
                    v[s].y = v[s].y * PM + f.y * PMC;
                    v[s].z = v[s].z * PM + f.z * PMC;
                    v[s].w = v[s].w * PM + f.w * PMC;
                    ss += v[s].x * v[s].x + v[s].y * v[s].y + v[s].z * v[s].z + v[s].w * v[s].w;
                }
                #pragma unroll
                for (int off = 32; off > 0; off >>= 1) ss += __shfl_xor(ss, off);
                const float inv = 1.0f / fmaxf(sqrtf(ss), 1e-12f);
                #pragma unroll
                for (int s = 0; s < 4; ++s) {
                    v[s].x *= inv; v[s].y *= inv; v[s].z *= inv; v[s].w *= inv;
                }
            }
        }

        // int8 quantize into LDS staging: k0 = s*256 + lane*4;
        // piece = k0>>4 = s*16 + (lane>>2), word = lane&3. |v|<=1 -> |q|<=127.
        #pragma unroll
        for (int s = 0; s < 4; ++s) {
            const int qx = __float2int_rn(v[s].x * 127.0f);
            const int qy = __float2int_rn(v[s].y * 127.0f);
            const int qz = __float2int_rn(v[s].z * 127.0f);
            const int qw = __float2int_rn(v[s].w * 127.0f);
            const unsigned int pk = (qx & 0xFF) | ((qy & 0xFF) << 8) |
                                    ((qz & 0xFF) << 16) | ((unsigned int)(qw & 0xFF) << 24);
            sq[s * 16 + (lane >> 2)][w * 4 + i][lane & 3] = pk;
        }
    }
    __syncthreads();

    // coalesced writeback: 1024 slots of 16 B (piece pp16, class cls)
    u8* base2 = P8 + (size_t)(cb >> 5) * 32768 + (cb & 31) * 16;
    #pragma unroll
    for (int it = 0; it < 4; ++it) {
        const int slot = it * 256 + t;
        const int pp16 = slot >> 4, cls = slot & 15;
        uint4 val;
        val.x = sq[pp16][cls][0]; val.y = sq[pp16][cls][1];
        val.z = sq[pp16][cls][2]; val.w = sq[pp16][cls][3];
        *(uint4*)(base2 + (pp16 >> 1) * 1024 + (pp16 & 1) * 512 + cls * 16) = val;
    }
}

// ---------------------------------------------------------------------------
// int8 Gram, mfma_i32_32x32x32_i8 (r23 pipeline verbatim per tile).
//
// r24 PACKING: r23's OccupancyPercent ~33% (avg ~10.6/32 waves) + 2080
// blocks over 1024 slots (2.03 rounds) = drain/imbalance tail. Persistent
// 1024 blocks, XCD-LOCAL static tile lists (this is what r14 got wrong --
// its lex assignment destroyed XCD-L2 locality, FETCH 67->114 MB; r15 fixed
// locality but swapped in a shallow pipeline; neither kept r13-pipeline +
// XCD-local lists together):
//   r = bb&7 -> XCD (empirical blockIdx%8 mapping, r13 FETCH-floor verified)
//   XCD r owns r13's 8 strips {r,15-r,16+r,31-r,32+r,47-r,48+r,63-r} = 260
//   slot s = bb>>3 takes local tiles {2s, 2s+1}; leftovers 256+e -> slots
//   {0,33,66,99} (distinct CUs: s mod 32 = 0,1,2,3). Per-CU 8 slots, 4 CUs 9.
// Per tile: r23's 5-buf ring, counted vmcnt (WAITV(4) at barrier kc
// certifies chunks kc+1,kc+2), cross-barrier PF prefetch, 4 ds_read_b128 +
// 4 MFMA per chunk. WAITV(0) before each prologue: drains prior epilogue's
// rowsum atomics so they don't inflate the counted-vmcnt discipline.
// Triangle cover bi<=bj; diag blocks mask li>=lj -> rowsum == sum_neg.
__global__ __launch_bounds__(256, 4) void gram8_kernel(const u8* __restrict__ P8,
                                                       float* __restrict__ rowsum) {
    __shared__ u8 lds[5][8192];      // per buf: A groups 0..3 @ g*1024, B @ 4096+
    const int t = threadIdx.x, w = t >> 6, lane = t & 63;
    const int bb = blockIdx.x;
    const int r = bb & 7;            // XCD
    const int s = bb >> 3;           // slot within XCD [0,128)

    const int ldsA = w * 1024, ldsB = 4096 + w * 1024;
    const int qi = w >> 1, qj = w & 1;
    const int aT0 = qi * 2048;                 // wave's A groups 2qi, 2qi+1
    const int bT0 = 4096 + qj * 2048;          // wave's B groups 2qj, 2qj+1
    const int alof = (lane >> 5) * 512 + (lane & 31) * 16;   // fragment addr in chunk

    int nt = 2, extra = 0;
    if (s == 0 || s == 33 || s == 66 || s == 99) { nt = 3; extra = 256 + s / 33; }

    i32x16 acc[2][2];
    i32x4 fa[2][2], fb[2][2];   // [reg set][tile]

#define STAGE(KC, BUF)                                                         \
    __builtin_amdgcn_global_load_lds(GLOBAL_AS(gsrcA + (size_t)(KC) * 1024),   \
                                     LDS_AS(&lds[BUF][ldsA]), 16, 0, 0);       \
    __builtin_amdgcn_global_load_lds(GLOBAL_AS(gsrcB + (size_t)(KC) * 1024),   \
                                     LDS_AS(&lds[BUF][ldsB]), 16, 0, 0);

#define PF(SET, BUF)                                                           \
    fa[SET][0] = *(const i32x4*)&lds[BUF][aT0 + alof];                         \
    fa[SET][1] = *(const i32x4*)&lds[BUF][aT0 + 1024 + alof];                  \
    fb[SET][0] = *(const i32x4*)&lds[BUF][bT0 + alof];                         \
    fb[SET][1] = *(const i32x4*)&lds[BUF][bT0 + 1024 + alof];

#define MFMA4(SET)                                                             \
    acc[0][0] = __builtin_amdgcn_mfma_i32_32x32x32_i8(fa[SET][0], fb[SET][0], acc[0][0], 0, 0, 0); \
    acc[0][1] = __builtin_amdgcn_mfma_i32_32x32x32_i8(fa[SET][0], fb[SET][1], acc[0][1], 0, 0, 0); \
    acc[1][0] = __builtin_amdgcn_mfma_i32_32x32x32_i8(fa[SET][1], fb[SET][0], acc[1][0], 0, 0, 0); \
    acc[1][1] = __builtin_amdgcn_mfma_i32_32x32x32_i8(fa[SET][1], fb[SET][1], acc[1][1], 0, 0, 0);

#define WAITV(N) asm volatile("s_waitcnt vmcnt(" #N ")" ::: "memory")

    for (int tt = 0; tt < nt; ++tt) {
        // XCD-local tile index -> (bi, bj) via strip walk (r13's cover)
        const int l = (tt == 2) ? extra : 2 * s + tt;
        int mm = l, bi = 0;
        #pragma unroll
        for (int s8 = 0; s8 < 8; ++s8) {
            const int strip = (s8 & 1) ? ((s8 >> 1) * 16 + 15 - r) : ((s8 >> 1) * 16 + r);
            const int n = 64 - strip;
            if (mm < n) { bi = strip; break; }
            mm -= n;
        }
        const int bj = bi + mm;
        const bool diag = (bi == bj);

        // per-wave staging: 2 glds x 1 KB per chunk (A group w, B group w)
        const u8* gsrcA = P8 + (size_t)(bi * 4 + w) * 32768 + lane * 16;
        const u8* gsrcB = P8 + (size_t)(bj * 4 + w) * 32768 + lane * 16;

        #pragma unroll
        for (int a = 0; a < 2; ++a)
            #pragma unroll
            for (int b = 0; b < 2; ++b)
                #pragma unroll
                for (int e = 0; e < 16; ++e) acc[a][b][e] = 0;

        // WAR vs previous tile's epilogue LDS scratch; no-op at tt=0
        __syncthreads();
        WAITV(0);   // drain prior epilogue atomics: counted-vmcnt starts clean

        // prologue: stage chunks 0..3 into bufs 0..3 (8 glds outstanding/wave)
        STAGE(0, 0); STAGE(1, 1); STAGE(2, 2); STAGE(3, 3);
        WAITV(4);                                // chunks 0,1 resident
        __builtin_amdgcn_s_barrier();
        PF(0, 0);                                // chunk 0 fragments

        int cbuf = 0;                            // buffer of chunk kc (kc % 5)
        for (int kc = 0; kc < 28; ++kc) {
            const int sb = (cbuf >= 1) ? cbuf - 1 : 4;    // (kc+4)%5: held kc-1
            STAGE(kc + 4, sb);
            const int nb = (cbuf == 4) ? 0 : cbuf + 1;    // buffer of chunk kc+1
            PF((kc + 1) & 1, nb);                // prefetch chunk kc+1 (certified)
            MFMA4(kc & 1);                       // chunk kc
            WAITV(4);                            // certifies chunks kc+1, kc+2
            __builtin_amdgcn_s_barrier();
            cbuf = nb;
        }
        // peeled tail: chunks 28..31 in bufs 3,4,0,1 (chunk 28 already in set 0)
        PF(1, 4);                                // chunk 29 (certified at barrier 27)
        MFMA4(0);                                // chunk 28
        WAITV(2); __builtin_amdgcn_s_barrier();  // certifies chunk 30
        PF(0, 0);                                // chunk 30
        MFMA4(1);                                // chunk 29
        WAITV(0); __builtin_amdgcn_s_barrier();  // certifies chunk 31
        PF(1, 1);                                // chunk 31
        MFMA4(0);                                // chunk 30
        MFMA4(1);                                // chunk 31

        // epilogue: exp(acc*10/16129), diag-block triangle mask, partials.
        // C layout (32x32, dtype-independent): col = lane&31,
        // row = (reg&3) + 8*(reg>>2) + 4*(lane>>5)
        __syncthreads();                         // K-loop fully done; lds reusable
        float* rpart = (float*)&lds[0][0];
        float* cpart = (float*)&lds[0][512];
        if (t < 128) { rpart[t] = 0.0f; cpart[t] = 0.0f; }
        __syncthreads();
        const int half = lane >> 5, col = lane & 31;
        float csum[2] = {0.0f, 0.0f};
        #pragma unroll
        for (int ti = 0; ti < 2; ++ti) {
            float rs[16];
            #pragma unroll
            for (int reg = 0; reg < 16; ++reg) rs[reg] = 0.0f;
            #pragma unroll
            for (int tj = 0; tj < 2; ++tj) {
                const int lj = qj * 64 + tj * 32 + col;
                #pragma unroll
                for (int reg = 0; reg < 16; ++reg) {
                    const int li = qi * 64 + ti * 32 + (reg & 3) + 8 * (reg >> 2) + 4 * half;
                    float e = __expf((float)acc[ti][tj][reg] * INVT_I8);
                    if (diag && li >= lj) e = 0.0f;  // bi<bj blocks: always li<lj globally
                    rs[reg] += e;
                    csum[tj] += e;
                }
            }
            #pragma unroll
            for (int reg = 0; reg < 16; ++reg) {
                float v = rs[reg];
                v += __shfl_xor(v, 1); v += __shfl_xor(v, 2); v += __shfl_xor(v, 4);
                v += __shfl_xor(v, 8); v += __shfl_xor(v, 16);
                if (col == 0)
                    atomicAdd(&rpart[qi * 64 + ti * 32 + (reg & 3) + 8 * (reg >> 2) + 4 * half], v);
            }
        }
        #pragma unroll
        for (int tj = 0; tj < 2; ++tj) {
            float v = csum[tj];
            v += __shfl_xor(v, 32);
            if (half == 0) atomicAdd(&cpart[qj * 64 + tj * 32 + col], v);
        }
        __syncthreads();
        if (t < 128) atomicAdd(&rowsum[bi * 128 + t], rpart[t]);
        else         atomicAdd(&rowsum[bj * 128 + (t - 128)], cpart[t - 128]);
    }
}

// ---------------------------------------------------------------------------
// rowsum == sum_neg (diag + lower triangle excluded in gram)
__global__ __launch_bounds__(256) void final2_kernel(const float* __restrict__ rowsum,
                                                     float* __restrict__ out) {
    __shared__ float red[4];
    const int t = threadIdx.x;
    const int i = blockIdx.x * 256 + t;
    float v = logf(rowsum[i] * (1.0f / (float)(C - 1)));
    #pragma unroll
    for (int off = 32; off > 0; off >>= 1) v += __shfl_down(v, off);
    if ((t & 63) == 0) red[t >> 6] = v;
    __syncthreads();
    if (t == 0)
        atomicAdd(out, (red[0] + red[1] + red[2] + red[3]) * (1.0f / (float)C));
}

// ---------------------------------------------------------------------------
extern "C" void kernel_launch(void* const* d_in, const int* in_sizes, int n_in,
                              void* d_out, int out_size, void* d_ws, size_t ws_size,
                              hipStream_t stream) {
    const float* feat = (const float*)d_in[0];
    const int* labels = (const int*)d_in[1];
    const float* protos = (const float*)d_in[2];
    float* out = (float*)d_out;
    float* rowsum = (float*)d_ws;               // 32 KB
    u8* P8 = (u8*)((char*)d_ws + 32768);        // 8 MiB packed int8 protos

    ema_split_kernel<<<C / 16, 256, 0, stream>>>(feat, labels, protos, P8, rowsum, out);
    gram8_kernel<<<1024, 256, 0, stream>>>(P8, rowsum);
    final2_kernel<<<C / 256, 256, 0, stream>>>(rowsum, out);
}

// Round 12
// 148.786 us; speedup vs baseline: 1.0288x; 1.0288x over previous
//
#include <hip/hip_runtime.h>
#include <math.h>

#define C 8192
#define D 1024
#define BATCH 1024
#define PM 0.95f
#define PMC 0.05f
// int8 quant with scale 127 per side; dot comes out 16129x too big.
// epilogue uses 10/16129 (INVT = 1/TEMP = 10).
#define INVT_I8 (10.0f / 16129.0f)

typedef unsigned char u8;
typedef __attribute__((ext_vector_type(16))) int i32x16;
typedef __attribute__((ext_vector_type(4))) int i32x4;

#define GLOBAL_AS(p) ((const __attribute__((address_space(1))) void*)(p))
#define LDS_AS(p) ((__attribute__((address_space(3))) void*)(p))

// ---------------------------------------------------------------------------
// EMA + int8 quantize (r23 exact, verified). 512 blocks x 16 consecutive
// classes; LDS-staged quantize + block-cooperative coalesced writeback.
// int8 layout (1-KB k-chunks per 32-row group, 16-B lane units for
// mfma_i32_32x32x32_i8, k = (l>>5)*16 + [0,16) contiguous):
//   element (row c, k) ->
//     P8[(c>>5)*32768 + (k>>5)*1024 + ((k>>4)&1)*512 + (c&31)*16 + (k&15)]
__global__ __launch_bounds__(256) void ema_split_kernel(const float* __restrict__ feat,
                                                        const int* __restrict__ labels,
                                                        const float* __restrict__ protos,
                                                        u8* __restrict__ P8,
                                                        float* __restrict__ rowsum,
                                                        float* __restrict__ out) {
    __shared__ int sl[BATCH];
    __shared__ unsigned int sq[64][16][4];    // [16B-piece][class-in-block][word]  16 KB
    const int t = threadIdx.x, w = t >> 6, lane = t & 63;
    const int cb = blockIdx.x * 16;

    if (blockIdx.x < 32) rowsum[blockIdx.x * 256 + t] = 0.0f;
    if (blockIdx.x == 0 && t == 0) out[0] = 0.0f;

    for (int i = t; i < BATCH; i += 256) sl[i] = labels[i];
    __syncthreads();

    for (int i = 0; i < 4; ++i) {
        const int c = cb + w * 4 + i;

        float4 v[4];
        #pragma unroll
        for (int s = 0; s < 4; ++s)
            v[s] = *(const float4*)(protos + (size_t)c * D + s * 256 + lane * 4);

        for (int base = 0; base < BATCH; base += 64) {
            unsigned long long mask = __ballot(sl[base + lane] == c);
            while (mask) {
                const int b = __ffsll((long long)mask) - 1;
                mask &= mask - 1;
                const int idx = base + b;
                float ss = 0.0f;
                #pragma unroll
                for (int s = 0; s < 4; ++s) {
                    const float4 f = *(const float4*)(feat + (size_t)idx * D + s * 256 + lane * 4);
                    v[s].x = v[s].x * PM + f.x * PMC;
                    v[s].y = v[s].y * PM + f.y * PMC;
                    v[s].z = v[s].z * PM + f.z * PMC;
                    v[s].w = v[s].w * PM + f.w * PMC;
                    ss += v[s].x * v[s].x + v[s].y * v[s].y + v[s].z * v[s].z + v[s].w * v[s].w;
                }
                #pragma unroll
                for (int off = 32; off > 0; off >>= 1) ss += __shfl_xor(ss, off);
                const float inv = 1.0f / fmaxf(sqrtf(ss), 1e-12f);
                #pragma unroll
                for (int s = 0; s < 4; ++s) {
                    v[s].x *= inv; v[s].y *= inv; v[s].z *= inv; v[s].w *= inv;
                }
            }
        }

        // int8 quantize into LDS staging: k0 = s*256 + lane*4;
        // piece = k0>>4 = s*16 + (lane>>2), word = lane&3. |v|<=1 -> |q|<=127.
        #pragma unroll
        for (int s = 0; s < 4; ++s) {
            const int qx = __float2int_rn(v[s].x * 127.0f);
            const int qy = __float2int_rn(v[s].y * 127.0f);
            const int qz = __float2int_rn(v[s].z * 127.0f);
            const int qw = __float2int_rn(v[s].w * 127.0f);
            const unsigned int pk = (qx & 0xFF) | ((qy & 0xFF) << 8) |
                                    ((qz & 0xFF) << 16) | ((unsigned int)(qw & 0xFF) << 24);
            sq[s * 16 + (lane >> 2)][w * 4 + i][lane & 3] = pk;
        }
    }
    __syncthreads();

    // coalesced writeback: 1024 slots of 16 B (piece pp16, class cls)
    u8* base2 = P8 + (size_t)(cb >> 5) * 32768 + (cb & 31) * 16;
    #pragma unroll
    for (int it = 0; it < 4; ++it) {
        const int slot = it * 256 + t;
        const int pp16 = slot >> 4, cls = slot & 15;
        uint4 val;
        val.x = sq[pp16][cls][0]; val.y = sq[pp16][cls][1];
        val.z = sq[pp16][cls][2]; val.w = sq[pp16][cls][3];
        *(uint4*)(base2 + (pp16 >> 1) * 1024 + (pp16 & 1) * 512 + cls * 16) = val;
    }
}

// ---------------------------------------------------------------------------
// int8 Gram, mfma_i32_32x32x32_i8. r23 VERBATIM -- best measured config
// (gram8 64.5 us, total 146.8). Session-final structure notes:
//  * i8 at 2x non-scaled-fp8 MFMA rate halved the MFMA-ideal 32->16 us
//    (r23's -14 us matched prediction exactly). mfma_scale path is unusable
//    on this toolchain (C/D operand round-trips scratch: 601 MB WRITE_SIZE
//    invariant under operand idiom + launch bounds, r20-r22).
//  * Rolling dispatch of 2080 blocks BEATS persistent packing (r14/r15/r24:
//    +6..+17 us): co-resident blocks start phase-staggered and fill each
//    other's barrier stalls; persistent blocks lockstep.
//  * Remaining ~48 us over MFMA-ideal is a sync/latency floor with NO
//    saturated pipe (MfmaUtil 21, VALU 22, LDS ~43%, HBM 13%, conflicts 0);
//    survived 7 structural variants. Escapes require trading the
//    40KB/4-block/16-wave occupancy sweet spot -- measured negative twice.
// Pipeline: 5-buffer ring, per-wave 2-gld staging, counted vmcnt (WAITV(4)
// at barrier kc certifies chunks kc+1,kc+2), cross-barrier register PF,
// one-barrier WAR separation; 4 ds_read_b128 + 4 MFMA per K=32 chunk.
// Triangle cover bi<=bj (2080 blocks, XCD strip swizzle: 260/XCD); diag
// blocks mask li>=lj -> rowsum == sum_neg.
__global__ __launch_bounds__(256, 4) void gram8_kernel(const u8* __restrict__ P8,
                                                       float* __restrict__ rowsum) {
    __shared__ u8 lds[5][8192];      // per buf: A groups 0..3 @ g*1024, B @ 4096+
    const int t = threadIdx.x, w = t >> 6, lane = t & 63;

    // swizzled block -> (bi, bj), bi <= bj, 128-row strips
    int mm = blockIdx.x >> 3;
    const int r = blockIdx.x & 7;
    int bi = 0;
    #pragma unroll
    for (int s = 0; s < 8; ++s) {
        const int strip = (s & 1) ? ((s >> 1) * 16 + 15 - r) : ((s >> 1) * 16 + r);
        const int n = 64 - strip;
        if (mm < n) { bi = strip; break; }
        mm -= n;
    }
    const int bj = bi + mm;
    const bool diag = (bi == bj);

    // per-wave staging: 2 glds x 1 KB per chunk (A group w, B group w)
    const u8* gsrcA = P8 + (size_t)(bi * 4 + w) * 32768 + lane * 16;
    const u8* gsrcB = P8 + (size_t)(bj * 4 + w) * 32768 + lane * 16;
    const int ldsA = w * 1024, ldsB = 4096 + w * 1024;

    const int qi = w >> 1, qj = w & 1;
    const int aT0 = qi * 2048;                 // wave's A groups 2qi, 2qi+1
    const int bT0 = 4096 + qj * 2048;          // wave's B groups 2qj, 2qj+1
    const int alof = (lane >> 5) * 512 + (lane & 31) * 16;   // fragment addr in chunk

    i32x16 acc[2][2];
    #pragma unroll
    for (int a = 0; a < 2; ++a)
        #pragma unroll
        for (int b = 0; b < 2; ++b)
            #pragma unroll
            for (int e = 0; e < 16; ++e) acc[a][b][e] = 0;

    i32x4 fa[2][2], fb[2][2];   // [reg set][tile]

#define STAGE(KC, BUF)                                                         \
    __builtin_amdgcn_global_load_lds(GLOBAL_AS(gsrcA + (size_t)(KC) * 1024),   \
                                     LDS_AS(&lds[BUF][ldsA]), 16, 0, 0);       \
    __builtin_amdgcn_global_load_lds(GLOBAL_AS(gsrcB + (size_t)(KC) * 1024),   \
                                     LDS_AS(&lds[BUF][ldsB]), 16, 0, 0);

#define PF(SET, BUF)                                                           \
    fa[SET][0] = *(const i32x4*)&lds[BUF][aT0 + alof];                         \
    fa[SET][1] = *(const i32x4*)&lds[BUF][aT0 + 1024 + alof];                  \
    fb[SET][0] = *(const i32x4*)&lds[BUF][bT0 + alof];                         \
    fb[SET][1] = *(const i32x4*)&lds[BUF][bT0 + 1024 + alof];

#define MFMA4(SET)                                                             \
    acc[0][0] = __builtin_amdgcn_mfma_i32_32x32x32_i8(fa[SET][0], fb[SET][0], acc[0][0], 0, 0, 0); \
    acc[0][1] = __builtin_amdgcn_mfma_i32_32x32x32_i8(fa[SET][0], fb[SET][1], acc[0][1], 0, 0, 0); \
    acc[1][0] = __builtin_amdgcn_mfma_i32_32x32x32_i8(fa[SET][1], fb[SET][0], acc[1][0], 0, 0, 0); \
    acc[1][1] = __builtin_amdgcn_mfma_i32_32x32x32_i8(fa[SET][1], fb[SET][1], acc[1][1], 0, 0, 0);

#define WAITV(N) asm volatile("s_waitcnt vmcnt(" #N ")" ::: "memory")

    // prologue: stage chunks 0..3 into bufs 0..3 (8 glds outstanding/wave)
    STAGE(0, 0); STAGE(1, 1); STAGE(2, 2); STAGE(3, 3);
    WAITV(4);                                // chunks 0,1 resident
    __builtin_amdgcn_s_barrier();
    PF(0, 0);                                // chunk 0 fragments

    int cbuf = 0;                            // buffer of chunk kc (kc % 5)
    for (int kc = 0; kc < 28; ++kc) {
        const int sb = (cbuf >= 1) ? cbuf - 1 : 4;    // (kc+4)%5: held kc-1
        STAGE(kc + 4, sb);
        const int nb = (cbuf == 4) ? 0 : cbuf + 1;    // buffer of chunk kc+1
        PF((kc + 1) & 1, nb);                // prefetch chunk kc+1 (certified)
        MFMA4(kc & 1);                       // chunk kc
        WAITV(4);                            // certifies chunks kc+1, kc+2
        __builtin_amdgcn_s_barrier();
        cbuf = nb;
    }
    // peeled tail: chunks 28..31 in bufs 3,4,0,1 (chunk 28 already in set 0)
    PF(1, 4);                                // chunk 29 (certified at barrier 27)
    MFMA4(0);                                // chunk 28
    WAITV(2); __builtin_amdgcn_s_barrier();  // certifies chunk 30
    PF(0, 0);                                // chunk 30
    MFMA4(1);                                // chunk 29
    WAITV(0); __builtin_amdgcn_s_barrier();  // certifies chunk 31
    PF(1, 1);                                // chunk 31
    MFMA4(0);                                // chunk 30
    MFMA4(1);                                // chunk 31

    // epilogue: exp(acc*10/16129), diag-block triangle mask, row/col partials.
    // C layout (32x32, dtype-independent): col = lane&31,
    // row = (reg&3) + 8*(reg>>2) + 4*(lane>>5)
    __syncthreads();                         // K-loop fully done; lds reusable
    float* rpart = (float*)&lds[0][0];
    float* cpart = (float*)&lds[0][512];
    if (t < 128) { rpart[t] = 0.0f; cpart[t] = 0.0f; }
    __syncthreads();
    const int half = lane >> 5, col = lane & 31;
    float csum[2] = {0.0f, 0.0f};
    #pragma unroll
    for (int ti = 0; ti < 2; ++ti) {
        float rs[16];
        #pragma unroll
        for (int reg = 0; reg < 16; ++reg) rs[reg] = 0.0f;
        #pragma unroll
        for (int tj = 0; tj < 2; ++tj) {
            const int lj = qj * 64 + tj * 32 + col;
            #pragma unroll
            for (int reg = 0; reg < 16; ++reg) {
                const int li = qi * 64 + ti * 32 + (reg & 3) + 8 * (reg >> 2) + 4 * half;
                float e = __expf((float)acc[ti][tj][reg] * INVT_I8);
                if (diag && li >= lj) e = 0.0f;      // bi<bj blocks: always li<lj globally
                rs[reg] += e;
                csum[tj] += e;
            }
        }
        #pragma unroll
        for (int reg = 0; reg < 16; ++reg) {
            float v = rs[reg];
            v += __shfl_xor(v, 1); v += __shfl_xor(v, 2); v += __shfl_xor(v, 4);
            v += __shfl_xor(v, 8); v += __shfl_xor(v, 16);
            if (col == 0)
                atomicAdd(&rpart[qi * 64 + ti * 32 + (reg & 3) + 8 * (reg >> 2) + 4 * half], v);
        }
    }
    #pragma unroll
    for (int tj = 0; tj < 2; ++tj) {
        float v = csum[tj];
        v += __shfl_xor(v, 32);
        if (half == 0) atomicAdd(&cpart[qj * 64 + tj * 32 + col], v);
    }
    __syncthreads();
    if (t < 128) atomicAdd(&rowsum[bi * 128 + t], rpart[t]);
    else         atomicAdd(&rowsum[bj * 128 + (t - 128)], cpart[t - 128]);
}

// ---------------------------------------------------------------------------
// rowsum == sum_neg (diag + lower triangle excluded in gram)
__global__ __launch_bounds__(256) void final2_kernel(const float* __restrict__ rowsum,
                                                     float* __restrict__ out) {
    __shared__ float red[4];
    const int t = threadIdx.x;
    const int i = blockIdx.x * 256 + t;
    float v = logf(rowsum[i] * (1.0f / (float)(C - 1)));
    #pragma unroll
    for (int off = 32; off > 0; off >>= 1) v += __shfl_down(v, off);
    if ((t & 63) == 0) red[t >> 6] = v;
    __syncthreads();
    if (t == 0)
        atomicAdd(out, (red[0] + red[1] + red[2] + red[3]) * (1.0f / (float)C));
}

// ---------------------------------------------------------------------------
extern "C" void kernel_launch(void* const* d_in, const int* in_sizes, int n_in,
                              void* d_out, int out_size, void* d_ws, size_t ws_size,
                              hipStream_t stream) {
    const float* feat = (const float*)d_in[0];
    const int* labels = (const int*)d_in[1];
    const float* protos = (const float*)d_in[2];
    float* out = (float*)d_out;
    float* rowsum = (float*)d_ws;               // 32 KB
    u8* P8 = (u8*)((char*)d_ws + 32768);        // 8 MiB packed int8 protos

    ema_split_kernel<<<C / 16, 256, 0, stream>>>(feat, labels, protos, P8, rowsum, out);
    gram8_kernel<<<2080, 256, 0, stream>>>(P8, rowsum);
    final2_kernel<<<C / 256, 256, 0, stream>>>(rowsum, out);
}

// Round 13
// 147.903 us; speedup vs baseline: 1.0349x; 1.0060x over previous
//
#include <hip/hip_runtime.h>
#include <math.h>

#define C 8192
#define D 1024
#define BATCH 1024
#define PM 0.95f
#define PMC 0.05f
// int8 quant with scale 127 per side; dot comes out 16129x too big.
// epilogue uses 10/16129 (INVT = 1/TEMP = 10).
#define INVT_I8 (10.0f / 16129.0f)

typedef unsigned char u8;
typedef __attribute__((ext_vector_type(16))) int i32x16;
typedef __attribute__((ext_vector_type(4))) int i32x4;

#define GLOBAL_AS(p) ((const __attribute__((address_space(1))) void*)(p))
#define LDS_AS(p) ((__attribute__((address_space(3))) void*)(p))

// ---------------------------------------------------------------------------
// EMA + int8 quantize (r23 exact, verified). 512 blocks x 16 consecutive
// classes; LDS-staged quantize + block-cooperative coalesced writeback.
// int8 layout (1-KB k-chunks per 32-row group, 16-B lane units for
// mfma_i32_32x32x32_i8, k = (l>>5)*16 + [0,16) contiguous):
//   element (row c, k) ->
//     P8[(c>>5)*32768 + (k>>5)*1024 + ((k>>4)&1)*512 + (c&31)*16 + (k&15)]
__global__ __launch_bounds__(256) void ema_split_kernel(const float* __restrict__ feat,
                                                        const int* __restrict__ labels,
                                                        const float* __restrict__ protos,
                                                        u8* __restrict__ P8,
                                                        float* __restrict__ rowsum,
                                                        float* __restrict__ out) {
    __shared__ int sl[BATCH];
    __shared__ unsigned int sq[64][16][4];    // [16B-piece][class-in-block][word]  16 KB
    const int t = threadIdx.x, w = t >> 6, lane = t & 63;
    const int cb = blockIdx.x * 16;

    if (blockIdx.x < 32) rowsum[blockIdx.x * 256 + t] = 0.0f;
    if (blockIdx.x == 0 && t == 0) out[0] = 0.0f;

    for (int i = t; i < BATCH; i += 256) sl[i] = labels[i];
    __syncthreads();

    for (int i = 0; i < 4; ++i) {
        const int c = cb + w * 4 + i;

        float4 v[4];
        #pragma unroll
        for (int s = 0; s < 4; ++s)
            v[s] = *(const float4*)(protos + (size_t)c * D + s * 256 + lane * 4);

        for (int base = 0; base < BATCH; base += 64) {
            unsigned long long mask = __ballot(sl[base + lane] == c);
            while (mask) {
                const int b = __ffsll((long long)mask) - 1;
                mask &= mask - 1;
                const int idx = base + b;
                float ss = 0.0f;
                #pragma unroll
                for (int s = 0; s < 4; ++s) {
                    const float4 f = *(const float4*)(feat + (size_t)idx * D + s * 256 + lane * 4);
                    v[s].x = v[s].x * PM + f.x * PMC;
                    v[s].y = v[s].y * PM + f.y * PMC;
                    v[s].z = v[s].z * PM + f.z * PMC;
                    v[s].w = v[s].w * PM + f.w * PMC;
                    ss += v[s].x * v[s].x + v[s].y * v[s].y + v[s].z * v[s].z + v[s].w * v[s].w;
                }
                #pragma unroll
                for (int off = 32; off > 0; off >>= 1) ss += __shfl_xor(ss, off);
                const float inv = 1.0f / fmaxf(sqrtf(ss), 1e-12f);
                #pragma unroll
                for (int s = 0; s < 4; ++s) {
                    v[s].x *= inv; v[s].y *= inv; v[s].z *= inv; v[s].w *= inv;
                }
            }
        }

        // int8 quantize into LDS staging: k0 = s*256 + lane*4;
        // piece = k0>>4 = s*16 + (lane>>2), word = lane&3. |v|<=1 -> |q|<=127.
        #pragma unroll
        for (int s = 0; s < 4; ++s) {
            const int qx = __float2int_rn(v[s].x * 127.0f);
            const int qy = __float2int_rn(v[s].y * 127.0f);
            const int qz = __float2int_rn(v[s].z * 127.0f);
            const int qw = __float2int_rn(v[s].w * 127.0f);
            const unsigned int pk = (qx & 0xFF) | ((qy & 0xFF) << 8) |
                                    ((qz & 0xFF) << 16) | ((unsigned int)(qw & 0xFF) << 24);
            sq[s * 16 + (lane >> 2)][w * 4 + i][lane & 3] = pk;
        }
    }
    __syncthreads();

    // coalesced writeback: 1024 slots of 16 B (piece pp16, class cls)
    u8* base2 = P8 + (size_t)(cb >> 5) * 32768 + (cb & 31) * 16;
    #pragma unroll
    for (int it = 0; it < 4; ++it) {
        const int slot = it * 256 + t;
        const int pp16 = slot >> 4, cls = slot & 15;
        uint4 val;
        val.x = sq[pp16][cls][0]; val.y = sq[pp16][cls][1];
        val.z = sq[pp16][cls][2]; val.w = sq[pp16][cls][3];
        *(uint4*)(base2 + (pp16 >> 1) * 1024 + (pp16 & 1) * 512 + cls * 16) = val;
    }
}

// ---------------------------------------------------------------------------
// int8 Gram, mfma_i32_32x32x32_i8.
//
// r27 OCCUPANCY FIX: every 40960-B round (r13/r16/r23/r26) measured
// OccupancyPercent 33-35% = ~3 blocks/CU, NOT the designed 4 -- the
// allocator cannot pack 4 x 40960 into the 160-KiB pool (163840 exactly;
// reservation/granularity). At 3 blocks the per-period wall (744 cyc) is
// ~1.3x the 3-block LDS-pipe floor (576 cyc) -- pipe-bound, one block
// short. Fix: ring 5 -> 4 buffers (32768 B) so 4 blocks genuinely fit.
//
// Ring-4 schedule (re-derived, same discipline as r13/r23):
//  * prologue stages chunks 0-2; WAITV(2) certifies 0,1.
//  * period kc: STAGE(kc+3 -> buf (kc+3)%4, which held chunk kc-1; its last
//    read was the PF of chunk kc-1 in period kc-2, >=2 barriers earlier);
//    PF chunk kc+1 (certified at barrier kc-1, which certified thru kc+1);
//    MFMA4(chunk kc); WAITV(2) (issued thru kc+3, leave its 2 glds
//    outstanding -> certifies thru kc+2, keeping next period's prefetch
//    legal); barrier. Latency slack ~1.5 periods (was 2) -- still > HBM
//    worst case at these period lengths.
// Everything else r23 verbatim: 2080 blocks + XCD strip swizzle (rolling
// dispatch beats persistent packing, r14/r15/r24), per-wave 2-gld staging,
// 4 ds_read_b128 + 4 MFMA per K=32 chunk, cross-barrier register PF.
// Triangle cover bi<=bj; diag blocks mask li>=lj -> rowsum == sum_neg.
__global__ __launch_bounds__(256, 4) void gram8_kernel(const u8* __restrict__ P8,
                                                       float* __restrict__ rowsum) {
    __shared__ u8 lds[4][8192];      // per buf: A groups 0..3 @ g*1024, B @ 4096+
    const int t = threadIdx.x, w = t >> 6, lane = t & 63;

    // swizzled block -> (bi, bj), bi <= bj, 128-row strips
    int mm = blockIdx.x >> 3;
    const int r = blockIdx.x & 7;
    int bi = 0;
    #pragma unroll
    for (int s = 0; s < 8; ++s) {
        const int strip = (s & 1) ? ((s >> 1) * 16 + 15 - r) : ((s >> 1) * 16 + r);
        const int n = 64 - strip;
        if (mm < n) { bi = strip; break; }
        mm -= n;
    }
    const int bj = bi + mm;
    const bool diag = (bi == bj);

    // per-wave staging: 2 glds x 1 KB per chunk (A group w, B group w)
    const u8* gsrcA = P8 + (size_t)(bi * 4 + w) * 32768 + lane * 16;
    const u8* gsrcB = P8 + (size_t)(bj * 4 + w) * 32768 + lane * 16;
    const int ldsA = w * 1024, ldsB = 4096 + w * 1024;

    const int qi = w >> 1, qj = w & 1;
    const int aT0 = qi * 2048;                 // wave's A groups 2qi, 2qi+1
    const int bT0 = 4096 + qj * 2048;          // wave's B groups 2qj, 2qj+1
    const int alof = (lane >> 5) * 512 + (lane & 31) * 16;   // fragment addr in chunk

    i32x16 acc[2][2];
    #pragma unroll
    for (int a = 0; a < 2; ++a)
        #pragma unroll
        for (int b = 0; b < 2; ++b)
            #pragma unroll
            for (int e = 0; e < 16; ++e) acc[a][b][e] = 0;

    i32x4 fa[2][2], fb[2][2];   // [reg set][tile]

#define STAGE(KC, BUF)                                                         \
    __builtin_amdgcn_global_load_lds(GLOBAL_AS(gsrcA + (size_t)(KC) * 1024),   \
                                     LDS_AS(&lds[BUF][ldsA]), 16, 0, 0);       \
    __builtin_amdgcn_global_load_lds(GLOBAL_AS(gsrcB + (size_t)(KC) * 1024),   \
                                     LDS_AS(&lds[BUF][ldsB]), 16, 0, 0);

#define PF(SET, BUF)                                                           \
    fa[SET][0] = *(const i32x4*)&lds[BUF][aT0 + alof];                         \
    fa[SET][1] = *(const i32x4*)&lds[BUF][aT0 + 1024 + alof];                  \
    fb[SET][0] = *(const i32x4*)&lds[BUF][bT0 + alof];                         \
    fb[SET][1] = *(const i32x4*)&lds[BUF][bT0 + 1024 + alof];

#define MFMA4(SET)                                                             \
    acc[0][0] = __builtin_amdgcn_mfma_i32_32x32x32_i8(fa[SET][0], fb[SET][0], acc[0][0], 0, 0, 0); \
    acc[0][1] = __builtin_amdgcn_mfma_i32_32x32x32_i8(fa[SET][0], fb[SET][1], acc[0][1], 0, 0, 0); \
    acc[1][0] = __builtin_amdgcn_mfma_i32_32x32x32_i8(fa[SET][1], fb[SET][0], acc[1][0], 0, 0, 0); \
    acc[1][1] = __builtin_amdgcn_mfma_i32_32x32x32_i8(fa[SET][1], fb[SET][1], acc[1][1], 0, 0, 0);

#define WAITV(N) asm volatile("s_waitcnt vmcnt(" #N ")" ::: "memory")

    // prologue: stage chunks 0..2 into bufs 0..2 (6 glds outstanding/wave)
    STAGE(0, 0); STAGE(1, 1); STAGE(2, 2);
    WAITV(2);                                // chunks 0,1 resident
    __builtin_amdgcn_s_barrier();
    PF(0, 0);                                // chunk 0 fragments

    int cbuf = 0;                            // buffer of chunk kc (kc % 4)
    for (int kc = 0; kc < 28; ++kc) {
        const int sb = (cbuf + 3) & 3;       // (kc+3)%4: held chunk kc-1
        STAGE(kc + 3, sb);
        const int nb = (cbuf + 1) & 3;       // buffer of chunk kc+1
        PF((kc + 1) & 1, nb);                // prefetch chunk kc+1 (certified)
        MFMA4(kc & 1);                       // chunk kc
        WAITV(2);                            // certifies thru chunk kc+2
        __builtin_amdgcn_s_barrier();
        cbuf = nb;
    }
    // tail: chunks 28..31 in bufs 0,1,2,3 (chunk 28 already in reg set 0)
    STAGE(31, 3);                            // buf3 held chunk 27 (read per.26)
    PF(1, 1);                                // chunk 29 (certified at barrier 27)
    MFMA4(0);                                // chunk 28
    WAITV(2); __builtin_amdgcn_s_barrier();  // certifies chunk 30
    PF(0, 2);                                // chunk 30
    MFMA4(1);                                // chunk 29
    WAITV(0); __builtin_amdgcn_s_barrier();  // certifies chunk 31
    PF(1, 3);                                // chunk 31
    MFMA4(0);                                // chunk 30
    MFMA4(1);                                // chunk 31

    // epilogue: exp(acc*10/16129), diag-block triangle mask, row/col partials.
    // C layout (32x32, dtype-independent): col = lane&31,
    // row = (reg&3) + 8*(reg>>2) + 4*(lane>>5)
    __syncthreads();                         // K-loop fully done; lds reusable
    float* rpart = (float*)&lds[0][0];
    float* cpart = (float*)&lds[0][512];
    if (t < 128) { rpart[t] = 0.0f; cpart[t] = 0.0f; }
    __syncthreads();
    const int half = lane >> 5, col = lane & 31;
    float csum[2] = {0.0f, 0.0f};
    #pragma unroll
    for (int ti = 0; ti < 2; ++ti) {
        float rs[16];
        #pragma unroll
        for (int reg = 0; reg < 16; ++reg) rs[reg] = 0.0f;
        #pragma unroll
        for (int tj = 0; tj < 2; ++tj) {
            const int lj = qj * 64 + tj * 32 + col;
            #pragma unroll
            for (int reg = 0; reg < 16; ++reg) {
                const int li = qi * 64 + ti * 32 + (reg & 3) + 8 * (reg >> 2) + 4 * half;
                float e = __expf((float)acc[ti][tj][reg] * INVT_I8);
                if (diag && li >= lj) e = 0.0f;      // bi<bj blocks: always li<lj globally
                rs[reg] += e;
                csum[tj] += e;
            }
        }
        #pragma unroll
        for (int reg = 0; reg < 16; ++reg) {
            float v = rs[reg];
            v += __shfl_xor(v, 1); v += __shfl_xor(v, 2); v += __shfl_xor(v, 4);
            v += __shfl_xor(v, 8); v += __shfl_xor(v, 16);
            if (col == 0)
                atomicAdd(&rpart[qi * 64 + ti * 32 + (reg & 3) + 8 * (reg >> 2) + 4 * half], v);
        }
    }
    #pragma unroll
    for (int tj = 0; tj < 2; ++tj) {
        float v = csum[tj];
        v += __shfl_xor(v, 32);
        if (half == 0) atomicAdd(&cpart[qj * 64 + tj * 32 + col], v);
    }
    __syncthreads();
    if (t < 128) atomicAdd(&rowsum[bi * 128 + t], rpart[t]);
    else         atomicAdd(&rowsum[bj * 128 + (t - 128)], cpart[t - 128]);
}

// ---------------------------------------------------------------------------
// rowsum == sum_neg (diag + lower triangle excluded in gram)
__global__ __launch_bounds__(256) void final2_kernel(const float* __restrict__ rowsum,
                                                     float* __restrict__ out) {
    __shared__ float red[4];
    const int t = threadIdx.x;
    const int i = blockIdx.x * 256 + t;
    float v = logf(rowsum[i] * (1.0f / (float)(C - 1)));
    #pragma unroll
    for (int off = 32; off > 0; off >>= 1) v += __shfl_down(v, off);
    if ((t & 63) == 0) red[t >> 6] = v;
    __syncthreads();
    if (t == 0)
        atomicAdd(out, (red[0] + red[1] + red[2] + red[3]) * (1.0f / (float)C));
}

// ---------------------------------------------------------------------------
extern "C" void kernel_launch(void* const* d_in, const int* in_sizes, int n_in,
                              void* d_out, int out_size, void* d_ws, size_t ws_size,
                              hipStream_t stream) {
    const float* feat = (const float*)d_in[0];
    const int* labels = (const int*)d_in[1];
    const float* protos = (const float*)d_in[2];
    float* out = (float*)d_out;
    float* rowsum = (float*)d_ws;               // 32 KB
    u8* P8 = (u8*)((char*)d_ws + 32768);        // 8 MiB packed int8 protos

    ema_split_kernel<<<C / 16, 256, 0, stream>>>(feat, labels, protos, P8, rowsum, out);
    gram8_kernel<<<2080, 256, 0, stream>>>(P8, rowsum);
    final2_kernel<<<C / 256, 256, 0, stream>>>(rowsum, out);
}

// Round 14
// 144.122 us; speedup vs baseline: 1.0621x; 1.0262x over previous
//
#include <hip/hip_runtime.h>
#include <math.h>

#define C 8192
#define D 1024
#define BATCH 1024
#define PM 0.95f
#define PMC 0.05f
// int8 quant with scale 127 per side; dot comes out 16129x too big.
// epilogue uses 10/16129 (INVT = 1/TEMP = 10).
#define INVT_I8 (10.0f / 16129.0f)

typedef unsigned char u8;
typedef __attribute__((ext_vector_type(16))) int i32x16;
typedef __attribute__((ext_vector_type(4))) int i32x4;

#define GLOBAL_AS(p) ((const __attribute__((address_space(1))) void*)(p))
#define LDS_AS(p) ((__attribute__((address_space(3))) void*)(p))

// ---------------------------------------------------------------------------
// EMA + int8 quantize (r23 exact, verified). 512 blocks x 16 consecutive
// classes; LDS-staged quantize + block-cooperative coalesced writeback.
// int8 layout (1-KB k-chunks per 32-row group, 16-B lane units for
// mfma_i32_32x32x32_i8, k = (l>>5)*16 + [0,16) contiguous):
//   element (row c, k) ->
//     P8[(c>>5)*32768 + (k>>5)*1024 + ((k>>4)&1)*512 + (c&31)*16 + (k&15)]
__global__ __launch_bounds__(256) void ema_split_kernel(const float* __restrict__ feat,
                                                        const int* __restrict__ labels,
                                                        const float* __restrict__ protos,
                                                        u8* __restrict__ P8,
                                                        float* __restrict__ rowsum,
                                                        float* __restrict__ out) {
    __shared__ int sl[BATCH];
    __shared__ unsigned int sq[64][16][4];    // [16B-piece][class-in-block][word]  16 KB
    const int t = threadIdx.x, w = t >> 6, lane = t & 63;
    const int cb = blockIdx.x * 16;

    if (blockIdx.x < 32) rowsum[blockIdx.x * 256 + t] = 0.0f;
    if (blockIdx.x == 0 && t == 0) out[0] = 0.0f;

    for (int i = t; i < BATCH; i += 256) sl[i] = labels[i];
    __syncthreads();

    for (int i = 0; i < 4; ++i) {
        const int c = cb + w * 4 + i;

        float4 v[4];
        #pragma unroll
        for (int s = 0; s < 4; ++s)
            v[s] = *(const float4*)(protos + (size_t)c * D + s * 256 + lane * 4);

        for (int base = 0; base < BATCH; base += 64) {
            unsigned long long mask = __ballot(sl[base + lane] == c);
            while (mask) {
                const int b = __ffsll((long long)mask) - 1;
                mask &= mask - 1;
                const int idx = base + b;
                float ss = 0.0f;
                #pragma unroll
                for (int s = 0; s < 4; ++s) {
                    const float4 f = *(const float4*)(feat + (size_t)idx * D + s * 256 + lane * 4);
                    v[s].x = v[s].x * PM + f.x * PMC;
                    v[s].y = v[s].y * PM + f.y * PMC;
                    v[s].z = v[s].z * PM + f.z * PMC;
                    v[s].w = v[s].w * PM + f.w * PMC;
                    ss += v[s].x * v[s].x + v[s].y * v[s].y + v[s].z * v[s].z + v[s].w * v[s].w;
                }
                #pragma unroll
                for (int off = 32; off > 0; off >>= 1) ss += __shfl_xor(ss, off);
                const float inv = 1.0f / fmaxf(sqrtf(ss), 1e-12f);
                #pragma unroll
                for (int s = 0; s < 4; ++s) {
                    v[s].x *= inv; v[s].y *= inv; v[s].z *= inv; v[s].w *= inv;
                }
            }
        }

        // int8 quantize into LDS staging: k0 = s*256 + lane*4;
        // piece = k0>>4 = s*16 + (lane>>2), word = lane&3. |v|<=1 -> |q|<=127.
        #pragma unroll
        for (int s = 0; s < 4; ++s) {
            const int qx = __float2int_rn(v[s].x * 127.0f);
            const int qy = __float2int_rn(v[s].y * 127.0f);
            const int qz = __float2int_rn(v[s].z * 127.0f);
            const int qw = __float2int_rn(v[s].w * 127.0f);
            const unsigned int pk = (qx & 0xFF) | ((qy & 0xFF) << 8) |
                                    ((qz & 0xFF) << 16) | ((unsigned int)(qw & 0xFF) << 24);
            sq[s * 16 + (lane >> 2)][w * 4 + i][lane & 3] = pk;
        }
    }
    __syncthreads();

    // coalesced writeback: 1024 slots of 16 B (piece pp16, class cls)
    u8* base2 = P8 + (size_t)(cb >> 5) * 32768 + (cb & 31) * 16;
    #pragma unroll
    for (int it = 0; it < 4; ++it) {
        const int slot = it * 256 + t;
        const int pp16 = slot >> 4, cls = slot & 15;
        uint4 val;
        val.x = sq[pp16][cls][0]; val.y = sq[pp16][cls][1];
        val.z = sq[pp16][cls][2]; val.w = sq[pp16][cls][3];
        *(uint4*)(base2 + (pp16 >> 1) * 1024 + (pp16 & 1) * 512 + cls * 16) = val;
    }
}

// ---------------------------------------------------------------------------
// int8 Gram, mfma_i32_32x32x32_i8. r23 VERBATIM -- session-best config
// (gram8 64.5 us, total 146.8). Final structure notes (13 rounds):
//  * i8 at 2x non-scaled-fp8 MFMA rate halved the MFMA-ideal 32->16 us
//    (r23 delta matched prediction). mfma_scale unusable on this toolchain
//    (C/D operand scratch round-trip: 601 MB WRITE_SIZE invariant under
//    operand idiom + launch bounds, r20-r22).
//  * Ring-5 depth is load-bearing: ring-4 (r27) cost +7.6 us gram8 --
//    2-period prefetch slack needed. Occupancy ~34% is ramp-diluted
//    4-block residency (identical at 32 KB and 40 KB LDS; r27 refuted the
//    3-block theory).
//  * Rolling dispatch of 2080 blocks BEATS persistent packing (r14/r24/r25).
//  * Residual 4.1x-over-ideal is a barrier-period latency floor with NO
//    saturated pipe (MfmaUtil 21, VALU 22, LDS ~21%, HBM 13%, conflicts 0);
//    per 595-cyc chunk-slot only ~146 cyc MFMA + ~128 cyc LDS are demanded.
//    Survived: sync-freq x2, barrier-free, persistent x3, occupancy trade,
//    ring-4, setprio, fused-final. All negative.
// Pipeline: 5-buffer ring, per-wave 2-gld staging, counted vmcnt (WAITV(4)
// at barrier kc certifies chunks kc+1,kc+2), cross-barrier register PF,
// one-barrier WAR separation; 4 ds_read_b128 + 4 MFMA per K=32 chunk.
// Triangle cover bi<=bj (2080 blocks, XCD strip swizzle: 260/XCD); diag
// blocks mask li>=lj -> rowsum == sum_neg.
__global__ __launch_bounds__(256, 4) void gram8_kernel(const u8* __restrict__ P8,
                                                       float* __restrict__ rowsum) {
    __shared__ u8 lds[5][8192];      // per buf: A groups 0..3 @ g*1024, B @ 4096+
    const int t = threadIdx.x, w = t >> 6, lane = t & 63;

    // swizzled block -> (bi, bj), bi <= bj, 128-row strips
    int mm = blockIdx.x >> 3;
    const int r = blockIdx.x & 7;
    int bi = 0;
    #pragma unroll
    for (int s = 0; s < 8; ++s) {
        const int strip = (s & 1) ? ((s >> 1) * 16 + 15 - r) : ((s >> 1) * 16 + r);
        const int n = 64 - strip;
        if (mm < n) { bi = strip; break; }
        mm -= n;
    }
    const int bj = bi + mm;
    const bool diag = (bi == bj);

    // per-wave staging: 2 glds x 1 KB per chunk (A group w, B group w)
    const u8* gsrcA = P8 + (size_t)(bi * 4 + w) * 32768 + lane * 16;
    const u8* gsrcB = P8 + (size_t)(bj * 4 + w) * 32768 + lane * 16;
    const int ldsA = w * 1024, ldsB = 4096 + w * 1024;

    const int qi = w >> 1, qj = w & 1;
    const int aT0 = qi * 2048;                 // wave's A groups 2qi, 2qi+1
    const int bT0 = 4096 + qj * 2048;          // wave's B groups 2qj, 2qj+1
    const int alof = (lane >> 5) * 512 + (lane & 31) * 16;   // fragment addr in chunk

    i32x16 acc[2][2];
    #pragma unroll
    for (int a = 0; a < 2; ++a)
        #pragma unroll
        for (int b = 0; b < 2; ++b)
            #pragma unroll
            for (int e = 0; e < 16; ++e) acc[a][b][e] = 0;

    i32x4 fa[2][2], fb[2][2];   // [reg set][tile]

#define STAGE(KC, BUF)                                                         \
    __builtin_amdgcn_global_load_lds(GLOBAL_AS(gsrcA + (size_t)(KC) * 1024),   \
                                     LDS_AS(&lds[BUF][ldsA]), 16, 0, 0);       \
    __builtin_amdgcn_global_load_lds(GLOBAL_AS(gsrcB + (size_t)(KC) * 1024),   \
                                     LDS_AS(&lds[BUF][ldsB]), 16, 0, 0);

#define PF(SET, BUF)                                                           \
    fa[SET][0] = *(const i32x4*)&lds[BUF][aT0 + alof];                         \
    fa[SET][1] = *(const i32x4*)&lds[BUF][aT0 + 1024 + alof];                  \
    fb[SET][0] = *(const i32x4*)&lds[BUF][bT0 + alof];                         \
    fb[SET][1] = *(const i32x4*)&lds[BUF][bT0 + 1024 + alof];

#define MFMA4(SET)                                                             \
    acc[0][0] = __builtin_amdgcn_mfma_i32_32x32x32_i8(fa[SET][0], fb[SET][0], acc[0][0], 0, 0, 0); \
    acc[0][1] = __builtin_amdgcn_mfma_i32_32x32x32_i8(fa[SET][0], fb[SET][1], acc[0][1], 0, 0, 0); \
    acc[1][0] = __builtin_amdgcn_mfma_i32_32x32x32_i8(fa[SET][1], fb[SET][0], acc[1][0], 0, 0, 0); \
    acc[1][1] = __builtin_amdgcn_mfma_i32_32x32x32_i8(fa[SET][1], fb[SET][1], acc[1][1], 0, 0, 0);

#define WAITV(N) asm volatile("s_waitcnt vmcnt(" #N ")" ::: "memory")

    // prologue: stage chunks 0..3 into bufs 0..3 (8 glds outstanding/wave)
    STAGE(0, 0); STAGE(1, 1); STAGE(2, 2); STAGE(3, 3);
    WAITV(4);                                // chunks 0,1 resident
    __builtin_amdgcn_s_barrier();
    PF(0, 0);                                // chunk 0 fragments

    int cbuf = 0;                            // buffer of chunk kc (kc % 5)
    for (int kc = 0; kc < 28; ++kc) {
        const int sb = (cbuf >= 1) ? cbuf - 1 : 4;    // (kc+4)%5: held kc-1
        STAGE(kc + 4, sb);
        const int nb = (cbuf == 4) ? 0 : cbuf + 1;    // buffer of chunk kc+1
        PF((kc + 1) & 1, nb);                // prefetch chunk kc+1 (certified)
        MFMA4(kc & 1);                       // chunk kc
        WAITV(4);                            // certifies chunks kc+1, kc+2
        __builtin_amdgcn_s_barrier();
        cbuf = nb;
    }
    // peeled tail: chunks 28..31 in bufs 3,4,0,1 (chunk 28 already in set 0)
    PF(1, 4);                                // chunk 29 (certified at barrier 27)
    MFMA4(0);                                // chunk 28
    WAITV(2); __builtin_amdgcn_s_barrier();  // certifies chunk 30
    PF(0, 0);                                // chunk 30
    MFMA4(1);                                // chunk 29
    WAITV(0); __builtin_amdgcn_s_barrier();  // certifies chunk 31
    PF(1, 1);                                // chunk 31
    MFMA4(0);                                // chunk 30
    MFMA4(1);                                // chunk 31

    // epilogue: exp(acc*10/16129), diag-block triangle mask, row/col partials.
    // C layout (32x32, dtype-independent): col = lane&31,
    // row = (reg&3) + 8*(reg>>2) + 4*(lane>>5)
    __syncthreads();                         // K-loop fully done; lds reusable
    float* rpart = (float*)&lds[0][0];
    float* cpart = (float*)&lds[0][512];
    if (t < 128) { rpart[t] = 0.0f; cpart[t] = 0.0f; }
    __syncthreads();
    const int half = lane >> 5, col = lane & 31;
    float csum[2] = {0.0f, 0.0f};
    #pragma unroll
    for (int ti = 0; ti < 2; ++ti) {
        float rs[16];
        #pragma unroll
        for (int reg = 0; reg < 16; ++reg) rs[reg] = 0.0f;
        #pragma unroll
        for (int tj = 0; tj < 2; ++tj) {
            const int lj = qj * 64 + tj * 32 + col;
            #pragma unroll
            for (int reg = 0; reg < 16; ++reg) {
                const int li = qi * 64 + ti * 32 + (reg & 3) + 8 * (reg >> 2) + 4 * half;
                float e = __expf((float)acc[ti][tj][reg] * INVT_I8);
                if (diag && li >= lj) e = 0.0f;      // bi<bj blocks: always li<lj globally
                rs[reg] += e;
                csum[tj] += e;
            }
        }
        #pragma unroll
        for (int reg = 0; reg < 16; ++reg) {
            float v = rs[reg];
            v += __shfl_xor(v, 1); v += __shfl_xor(v, 2); v += __shfl_xor(v, 4);
            v += __shfl_xor(v, 8); v += __shfl_xor(v, 16);
            if (col == 0)
                atomicAdd(&rpart[qi * 64 + ti * 32 + (reg & 3) + 8 * (reg >> 2) + 4 * half], v);
        }
    }
    #pragma unroll
    for (int tj = 0; tj < 2; ++tj) {
        float v = csum[tj];
        v += __shfl_xor(v, 32);
        if (half == 0) atomicAdd(&cpart[qj * 64 + tj * 32 + col], v);
    }
    __syncthreads();
    if (t < 128) atomicAdd(&rowsum[bi * 128 + t], rpart[t]);
    else         atomicAdd(&rowsum[bj * 128 + (t - 128)], cpart[t - 128]);
}

// ---------------------------------------------------------------------------
// rowsum == sum_neg (diag + lower triangle excluded in gram)
__global__ __launch_bounds__(256) void final2_kernel(const float* __restrict__ rowsum,
                                                     float* __restrict__ out) {
    __shared__ float red[4];
    const int t = threadIdx.x;
    const int i = blockIdx.x * 256 + t;
    float v = logf(rowsum[i] * (1.0f / (float)(C - 1)));
    #pragma unroll
    for (int off = 32; off > 0; off >>= 1) v += __shfl_down(v, off);
    if ((t & 63) == 0) red[t >> 6] = v;
    __syncthreads();
    if (t == 0)
        atomicAdd(out, (red[0] + red[1] + red[2] + red[3]) * (1.0f / (float)C));
}

// ---------------------------------------------------------------------------
extern "C" void kernel_launch(void* const* d_in, const int* in_sizes, int n_in,
                              void* d_out, int out_size, void* d_ws, size_t ws_size,
                              hipStream_t stream) {
    const float* feat = (const float*)d_in[0];
    const int* labels = (const int*)d_in[1];
    const float* protos = (const float*)d_in[2];
    float* out = (float*)d_out;
    float* rowsum = (float*)d_ws;               // 32 KB
    u8* P8 = (u8*)((char*)d_ws + 32768);        // 8 MiB packed int8 protos

    ema_split_kernel<<<C / 16, 256, 0, stream>>>(feat, labels, protos, P8, rowsum, out);
    gram8_kernel<<<2080, 256, 0, stream>>>(P8, rowsum);
    final2_kernel<<<C / 256, 256, 0, stream>>>(rowsum, out);
}